// Round 10
// baseline (419.768 us; speedup 1.0000x reference)
//
#include <hip/hip_runtime.h>
#include <cstdint>
#include <cstddef>

typedef unsigned short u16;
typedef __attribute__((ext_vector_type(8))) _Float16 f16x8;
typedef __attribute__((ext_vector_type(4))) float f32x4;
typedef __attribute__((ext_vector_type(2))) unsigned u32x2;
typedef __attribute__((ext_vector_type(4))) unsigned u32x4;

// ---------------- fp16 helpers ---------------------------------------------
__device__ __forceinline__ u16 f2h(float f) {
    union { _Float16 h; u16 u; } v; v.h = (_Float16)f;
    return v.u;
}
__device__ __forceinline__ float h2f(u16 b) {
    union { u16 u; _Float16 h; } v; v.u = b;
    return (float)v.h;
}
__device__ __forceinline__ float h2f_lo(unsigned w) { return h2f((u16)(w & 0xFFFFu)); }
__device__ __forceinline__ float h2f_hi(unsigned w) { return h2f((u16)(w >> 16)); }

__device__ __forceinline__ void gload16(const u16* g, u16* l) {
    __builtin_amdgcn_global_load_lds(
        (const __attribute__((address_space(1))) void*)g,
        (__attribute__((address_space(3))) void*)l, 16, 0, 0);
}

// ---------------- prep: zero deg/cursor || x->fp16 || weight transpose -----
// block ranges: [0,nbXs) xsplit, [nbXs,nbXs+208) wtrans, rest zero.
__global__ void prep_kernel(const float* __restrict__ x, u16* __restrict__ xh, int total8,
                            const float* __restrict__ W1, const float* __restrict__ W2,
                            const float* __restrict__ Wl, u16* __restrict__ bt1,
                            u16* __restrict__ bt2, u16* __restrict__ bt3,
                            int* __restrict__ deg, int* __restrict__ cursor, int n, int nbXs) {
    const int b = blockIdx.x;
    if (b < nbXs) {
        const int idx = b * 256 + threadIdx.x;
        if (idx >= total8) return;
        const float4 v0 = *(const float4*)(x + (size_t)idx * 8);
        const float4 v1 = *(const float4*)(x + (size_t)idx * 8 + 4);
        alignas(16) u16 h8[8];
        h8[0] = f2h(v0.x); h8[1] = f2h(v0.y); h8[2] = f2h(v0.z); h8[3] = f2h(v0.w);
        h8[4] = f2h(v1.x); h8[5] = f2h(v1.y); h8[6] = f2h(v1.z); h8[7] = f2h(v1.w);
        *(uint4*)(xh + (size_t)idx * 8) = *(const uint4*)h8;
    } else if (b < nbXs + 208) {
        int idx = (b - nbXs) * 256 + threadIdx.x;
        const float* W;
        u16* bt;
        int K, N;
        if (idx < 16384) {
            W = W1; bt = bt1; K = 256; N = 512;
        } else if (idx < 16384 + 32768) {
            idx -= 16384;
            W = W2; bt = bt2; K = 512; N = 512;
        } else if (idx < 16384 + 32768 + 4096) {
            idx -= 16384 + 32768;
            W = Wl; bt = bt3; K = 512; N = 64;
        } else {
            return;
        }
        const int k8 = K >> 3;
        const int nn = idx / k8;
        const int k0 = (idx - nn * k8) * 8;
        alignas(16) u16 h8[8];
#pragma unroll
        for (int j = 0; j < 8; j++) h8[j] = f2h(W[(size_t)(k0 + j) * N + nn]);
        *(uint4*)(bt + (size_t)nn * K + k0) = *(const uint4*)h8;
    } else {
        const int idx = (b - nbXs - 208) * 256 + threadIdx.x;
        if (idx < n) {
            deg[idx] = 0;
            cursor[idx] = 0;
        }
    }
}

// ---------------- graph setup ----------------------------------------------
__global__ void count_deg_kernel(const int* __restrict__ dst, int* __restrict__ deg, int e) {
    int i = blockIdx.x * blockDim.x + threadIdx.x;
    if (i < e) atomicAdd(&deg[dst[i]], 1);
}

__global__ __launch_bounds__(1024)
void scan1_kernel(const int* __restrict__ deg, int* __restrict__ part, int n) {
    __shared__ int sm[1024];
    const int t = threadIdx.x;
    const int i = blockIdx.x * 1024 + t;
    sm[t] = (i < n) ? deg[i] : 0;
    __syncthreads();
    for (int off = 512; off > 0; off >>= 1) {
        if (t < off) sm[t] += sm[t + off];
        __syncthreads();
    }
    if (t == 0) part[blockIdx.x] = sm[0];
}

// scan3 with inlined cross-block prefix (each thread sums part[0..b-1]).
__global__ __launch_bounds__(1024)
void scan3_kernel(const int* __restrict__ deg, const int* __restrict__ part,
                  float* __restrict__ dinv, int* __restrict__ row_start, int n) {
    __shared__ int sm[1024];
    const int t = threadIdx.x;
    const int b = blockIdx.x;
    const int i = b * 1024 + t;
    int base = 0;
    for (int j = 0; j < b; j++) base += part[j];  // <=48 L1-cached loads
    int v = 0;
    if (i < n) v = deg[i];
    sm[t] = v;
    __syncthreads();
    for (int off = 1; off < 1024; off <<= 1) {
        int tv = (t >= off) ? sm[t - off] : 0;
        __syncthreads();
        sm[t] += tv;
        __syncthreads();
    }
    if (i < n) {
        row_start[i] = base + sm[t] - v;
        dinv[i] = rsqrtf(1.0f + (float)v);  // +1 self-loop
    }
    if (i == n - 1) row_start[n] = base + sm[t];
}

__global__ void bucket_kernel(const int* __restrict__ src, const int* __restrict__ dst,
                              const int* __restrict__ row_start, int* __restrict__ cursor,
                              int* __restrict__ csr, float* __restrict__ csr_w,
                              const float* __restrict__ dinv, int e) {
    int i = blockIdx.x * blockDim.x + threadIdx.x;
    if (i < e) {
        int d = dst[i];
        int s = src[i];
        int pos = atomicAdd(&cursor[d], 1);
        int at = row_start[d] + pos;
        csr[at] = s;
        csr_w[at] = dinv[s] * dinv[d];
    }
}

// ---------------- layer-1 aggregation (x fp16 gather, F=256) ---------------
// grid-stride over nodes; 4 nodes (waves) per block.
__global__ __launch_bounds__(256)
void agg_x_kernel(const u16* __restrict__ xh, u16* __restrict__ oh,
                  const int* __restrict__ csr, const float* __restrict__ csr_w,
                  const int* __restrict__ rs, const float* __restrict__ dinv, int n) {
    const int lane = threadIdx.x & 63;
    const int c0 = lane * 4;
    const int stride = gridDim.x * 4;
    for (int node = blockIdx.x * 4 + (threadIdx.x >> 6); node < n; node += stride) {
        const int beg = rs[node], end = rs[node + 1];
        float a0 = 0.f, a1 = 0.f, a2 = 0.f, a3 = 0.f;
        int i = beg;
        for (; i + 8 <= end; i += 8) {
            int s[8];
            float w[8];
            uint2 hv[8];
#pragma unroll
            for (int u = 0; u < 8; u++) {
                s[u] = __builtin_nontemporal_load(csr + i + u);
                w[u] = __builtin_nontemporal_load(csr_w + i + u);
            }
#pragma unroll
            for (int u = 0; u < 8; u++) hv[u] = *(const uint2*)(xh + (size_t)s[u] * 256 + c0);
#pragma unroll
            for (int u = 0; u < 8; u++) {
                a0 = fmaf(h2f_lo(hv[u].x), w[u], a0);
                a1 = fmaf(h2f_hi(hv[u].x), w[u], a1);
                a2 = fmaf(h2f_lo(hv[u].y), w[u], a2);
                a3 = fmaf(h2f_hi(hv[u].y), w[u], a3);
            }
        }
        for (; i < end; i++) {
            const int sv = csr[i];
            const float w = csr_w[i];
            uint2 hv = *(const uint2*)(xh + (size_t)sv * 256 + c0);
            a0 = fmaf(h2f_lo(hv.x), w, a0);
            a1 = fmaf(h2f_hi(hv.x), w, a1);
            a2 = fmaf(h2f_lo(hv.y), w, a2);
            a3 = fmaf(h2f_hi(hv.y), w, a3);
        }
        {
            const float dn = dinv[node];
            const float ws = dn * dn;
            uint2 hv = *(const uint2*)(xh + (size_t)node * 256 + c0);
            a0 = fmaf(h2f_lo(hv.x), ws, a0);
            a1 = fmaf(h2f_hi(hv.x), ws, a1);
            a2 = fmaf(h2f_lo(hv.y), ws, a2);
            a3 = fmaf(h2f_hi(hv.y), ws, a3);
        }
        u32x2 ho;
        ho.x = (unsigned)f2h(a0) | ((unsigned)f2h(a1) << 16);
        ho.y = (unsigned)f2h(a2) | ((unsigned)f2h(a3) << 16);
        __builtin_nontemporal_store(ho, (u32x2*)(oh + (size_t)node * 256 + c0));
    }
}

// ---------------- layer-2 aggregation (h1 fp16 gather, F=512) --------------
__global__ __launch_bounds__(256)
void agg_h_kernel(const u16* __restrict__ hin, u16* __restrict__ oh,
                  const int* __restrict__ csr, const float* __restrict__ csr_w,
                  const int* __restrict__ rs, const float* __restrict__ dinv, int n) {
    const int lane = threadIdx.x & 63;
    const int c0 = lane * 8;
    const int stride = gridDim.x * 4;
    for (int node = blockIdx.x * 4 + (threadIdx.x >> 6); node < n; node += stride) {
        const int beg = rs[node], end = rs[node + 1];
        float a[8];
#pragma unroll
        for (int j = 0; j < 8; j++) a[j] = 0.f;
        int i = beg;
        for (; i + 8 <= end; i += 8) {
            int s[8];
            float w[8];
            uint4 hv[8];
#pragma unroll
            for (int u = 0; u < 8; u++) {
                s[u] = __builtin_nontemporal_load(csr + i + u);
                w[u] = __builtin_nontemporal_load(csr_w + i + u);
            }
#pragma unroll
            for (int u = 0; u < 8; u++) hv[u] = *(const uint4*)(hin + (size_t)s[u] * 512 + c0);
#pragma unroll
            for (int u = 0; u < 8; u++) {
                a[0] = fmaf(h2f_lo(hv[u].x), w[u], a[0]);
                a[1] = fmaf(h2f_hi(hv[u].x), w[u], a[1]);
                a[2] = fmaf(h2f_lo(hv[u].y), w[u], a[2]);
                a[3] = fmaf(h2f_hi(hv[u].y), w[u], a[3]);
                a[4] = fmaf(h2f_lo(hv[u].z), w[u], a[4]);
                a[5] = fmaf(h2f_hi(hv[u].z), w[u], a[5]);
                a[6] = fmaf(h2f_lo(hv[u].w), w[u], a[6]);
                a[7] = fmaf(h2f_hi(hv[u].w), w[u], a[7]);
            }
        }
        for (; i < end; i++) {
            const int sv = csr[i];
            const float w = csr_w[i];
            uint4 hv = *(const uint4*)(hin + (size_t)sv * 512 + c0);
            a[0] = fmaf(h2f_lo(hv.x), w, a[0]);
            a[1] = fmaf(h2f_hi(hv.x), w, a[1]);
            a[2] = fmaf(h2f_lo(hv.y), w, a[2]);
            a[3] = fmaf(h2f_hi(hv.y), w, a[3]);
            a[4] = fmaf(h2f_lo(hv.z), w, a[4]);
            a[5] = fmaf(h2f_hi(hv.z), w, a[5]);
            a[6] = fmaf(h2f_lo(hv.w), w, a[6]);
            a[7] = fmaf(h2f_hi(hv.w), w, a[7]);
        }
        {
            const float dn = dinv[node];
            const float ws = dn * dn;
            uint4 hv = *(const uint4*)(hin + (size_t)node * 512 + c0);
            a[0] = fmaf(h2f_lo(hv.x), ws, a[0]);
            a[1] = fmaf(h2f_hi(hv.x), ws, a[1]);
            a[2] = fmaf(h2f_lo(hv.y), ws, a[2]);
            a[3] = fmaf(h2f_hi(hv.y), ws, a[3]);
            a[4] = fmaf(h2f_lo(hv.z), ws, a[4]);
            a[5] = fmaf(h2f_hi(hv.z), ws, a[5]);
            a[6] = fmaf(h2f_lo(hv.w), ws, a[6]);
            a[7] = fmaf(h2f_hi(hv.w), ws, a[7]);
        }
        u32x4 ho;
#pragma unroll
        for (int j = 0; j < 4; j++)
            ho[j] = (unsigned)f2h(a[2 * j]) | ((unsigned)f2h(a[2 * j + 1]) << 16);
        __builtin_nontemporal_store(ho, (u32x4*)(oh + (size_t)node * 512 + c0));
    }
}

// ---------------- fp16 MFMA GEMM, BM=128 BN=256, 8 waves, LDS dbuf ---------
template <bool RELU, int OUTMODE>
__global__ __launch_bounds__(512)
void gemm256_kernel(const u16* __restrict__ A, const u16* __restrict__ Bt,
                    const float* __restrict__ bias,
                    float* __restrict__ Cf, u16* __restrict__ Ch,
                    int M, int K, int Nn) {
    __shared__ u16 sA[2][128 * 32], sB[2][256 * 32];

    const int gx = gridDim.x;
    const int nwg = gx * gridDim.y;
    const int orig = blockIdx.y * gx + blockIdx.x;
    const int q8 = nwg >> 3, r8 = nwg & 7;
    const int xcd = orig & 7, lin = orig >> 3;
    const int wg = (xcd < r8 ? xcd * (q8 + 1) : r8 * (q8 + 1) + (xcd - r8) * q8) + lin;
    const int mt = wg / gx;
    const int nt_ = wg - mt * gx;
    const int m0 = mt * 128, n0 = nt_ * 256;

    const int tid = threadIdx.x;
    const int lane = tid & 63;
    const int wid = tid >> 6;
    const int wm = (wid >> 2) * 64;
    const int wn = (wid & 3) * 64;

    const int srow = tid >> 2;
    const int gslot = (tid & 3) ^ ((tid >> 3) & 3);
    const int lbase = wid * 16 * 32;  // u16 units

    const u16* gA  = A  + (size_t)(m0 + srow) * K + gslot * 8;
    const u16* gB0 = Bt + (size_t)(n0 + srow) * K + gslot * 8;
    const u16* gB1 = Bt + (size_t)(n0 + 128 + srow) * K + gslot * 8;

    int offA[4], offB[4];
    const int q = lane >> 4;
#pragma unroll
    for (int i = 0; i < 4; i++) {
        int r = wm + i * 16 + (lane & 15);
        offA[i] = r * 32 + ((q ^ ((r >> 1) & 3)) * 8);
    }
#pragma unroll
    for (int j = 0; j < 4; j++) {
        int r = wn + j * 16 + (lane & 15);
        offB[j] = r * 32 + ((q ^ ((r >> 1) & 3)) * 8);
    }

    f32x4 acc[4][4];
#pragma unroll
    for (int i = 0; i < 4; i++)
#pragma unroll
        for (int j = 0; j < 4; j++) acc[i][j] = (f32x4){0.f, 0.f, 0.f, 0.f};

    auto stage = [&](int k0, int b) {
        gload16(gA + k0, sA[b] + lbase);
        gload16(gB0 + k0, sB[b] + lbase);
        gload16(gB1 + k0, sB[b] + 128 * 32 + lbase);
    };

    const int ntiles = K >> 5;
    stage(0, 0);
    for (int t = 0; t < ntiles; ++t) {
        const int cur = t & 1;
        __builtin_amdgcn_s_barrier();
        if (t + 1 < ntiles) {
            stage((t + 1) << 5, cur ^ 1);
            asm volatile("s_waitcnt vmcnt(3)" ::: "memory");
        } else {
            asm volatile("s_waitcnt vmcnt(0)" ::: "memory");
        }
        __builtin_amdgcn_s_barrier();
        __builtin_amdgcn_sched_barrier(0);

        f16x8 af[4], bf4[4];
#pragma unroll
        for (int i = 0; i < 4; i++) af[i] = *(const f16x8*)(sA[cur] + offA[i]);
#pragma unroll
        for (int j = 0; j < 4; j++) bf4[j] = *(const f16x8*)(sB[cur] + offB[j]);
#pragma unroll
        for (int i = 0; i < 4; i++)
#pragma unroll
            for (int j = 0; j < 4; j++)
                acc[i][j] = __builtin_amdgcn_mfma_f32_16x16x32_f16(af[i], bf4[j], acc[i][j], 0, 0, 0);
    }

    const int cn = lane & 15;
    const int cm = (lane >> 4) * 4;
#pragma unroll
    for (int i = 0; i < 4; i++) {
#pragma unroll
        for (int j = 0; j < 4; j++) {
            const int col = n0 + wn + j * 16 + cn;
            const float bv = bias[col];
#pragma unroll
            for (int r = 0; r < 4; r++) {
                const int row = m0 + wm + i * 16 + cm + r;
                if (row < M) {
                    float v = acc[i][j][r] + bv;
                    if (RELU) v = fmaxf(v, 0.f);
                    if constexpr (OUTMODE == 2) {
                        Ch[(size_t)row * Nn + col] = f2h(v);
                    } else {
                        Cf[(size_t)row * Nn + col] = v;
                    }
                }
            }
        }
    }
}

// ---------------- fp16 MFMA GEMM, BM=128 BN=64, 4 waves (2x2) --------------
template <bool RELU>
__global__ __launch_bounds__(256)
void gemm64_kernel(const u16* __restrict__ A, const u16* __restrict__ Bt,
                   const float* __restrict__ bias, float* __restrict__ Cf,
                   int M, int K, int Nn) {
    __shared__ u16 sA[128 * 32], sB[64 * 32];

    const int nwg = gridDim.y;
    const int orig = blockIdx.y;
    const int q8 = nwg >> 3, r8 = nwg & 7;
    const int xcd = orig & 7, lin = orig >> 3;
    const int wg = (xcd < r8 ? xcd * (q8 + 1) : r8 * (q8 + 1) + (xcd - r8) * q8) + lin;
    const int m0 = wg * 128, n0 = 0;

    const int tid = threadIdx.x;
    const int lane = tid & 63;
    const int wid = tid >> 6;
    const int wm = (wid >> 1) * 64;
    const int wn = (wid & 1) * 32;

    const int srow = tid >> 2;
    const int gslot = (tid & 3) ^ ((tid >> 3) & 3);
    const int lbase = wid * 16 * 32;

    const u16* gA0 = A + (size_t)(m0 + srow) * K + gslot * 8;
    const u16* gA1 = A + (size_t)(m0 + 64 + srow) * K + gslot * 8;
    const u16* gB0 = Bt + (size_t)(n0 + srow) * K + gslot * 8;

    int offA[4], offB[2];
    const int q = lane >> 4;
#pragma unroll
    for (int i = 0; i < 4; i++) {
        int r = wm + i * 16 + (lane & 15);
        offA[i] = r * 32 + ((q ^ ((r >> 1) & 3)) * 8);
    }
#pragma unroll
    for (int j = 0; j < 2; j++) {
        int r = wn + j * 16 + (lane & 15);
        offB[j] = r * 32 + ((q ^ ((r >> 1) & 3)) * 8);
    }

    f32x4 acc[4][2];
#pragma unroll
    for (int i = 0; i < 4; i++)
#pragma unroll
        for (int j = 0; j < 2; j++) acc[i][j] = (f32x4){0.f, 0.f, 0.f, 0.f};

    auto stage = [&](int k0) {
        gload16(gA0 + k0, sA + lbase);
        gload16(gA1 + k0, sA + 64 * 32 + lbase);
        gload16(gB0 + k0, sB + lbase);
    };

    stage(0);
    for (int k0 = 0; k0 < K; k0 += 32) {
        __syncthreads();
        f16x8 af[4], bf4[2];
#pragma unroll
        for (int i = 0; i < 4; i++) af[i] = *(const f16x8*)(sA + offA[i]);
#pragma unroll
        for (int j = 0; j < 2; j++) bf4[j] = *(const f16x8*)(sB + offB[j]);
#pragma unroll
        for (int i = 0; i < 4; i++)
#pragma unroll
            for (int j = 0; j < 2; j++)
                acc[i][j] = __builtin_amdgcn_mfma_f32_16x16x32_f16(af[i], bf4[j], acc[i][j], 0, 0, 0);
        __syncthreads();
        if (k0 + 32 < K) stage(k0 + 32);
    }

    const int cn = lane & 15;
    const int cm = (lane >> 4) * 4;
#pragma unroll
    for (int i = 0; i < 4; i++) {
#pragma unroll
        for (int j = 0; j < 2; j++) {
            const int col = wn + j * 16 + cn;
            const float bv = bias[col];
#pragma unroll
            for (int r = 0; r < 4; r++) {
                const int row = m0 + wm + i * 16 + cm + r;
                if (row < M) {
                    float v = acc[i][j][r] + bv;
                    if (RELU) v = fmaxf(v, 0.f);
                    Cf[(size_t)row * Nn + col] = v;
                }
            }
        }
    }
}

// ---------------------------------------------------------------------------
extern "C" void kernel_launch(void* const* d_in, const int* in_sizes, int n_in,
                              void* d_out, int out_size, void* d_ws, size_t ws_size,
                              hipStream_t stream) {
    const float* x  = (const float*)d_in[0];
    const int*   ei = (const int*)d_in[1];
    const float* W1 = (const float*)d_in[2];
    const float* b1 = (const float*)d_in[3];
    const float* W2 = (const float*)d_in[4];
    const float* b2 = (const float*)d_in[5];
    const float* Wl = (const float*)d_in[6];
    const float* bl = (const float*)d_in[7];
    float* out = (float*)d_out;

    const int N = in_sizes[0] / 256;  // 50000
    const int E = in_sizes[1] / 2;    // 800000
    const int Mpad = ((N + 127) / 128) * 128;  // 50048
    const int nb = (N + 1023) / 1024;
    const int* src = ei;
    const int* dst = ei + E;

    size_t off = 0;
    auto alloc = [&](size_t bytes) -> void* {
        void* p = (char*)d_ws + off;
        off += (bytes + 255) & ~(size_t)255;
        return p;
    };
    int*   deg       = (int*)alloc((size_t)N * 4);
    float* dinv      = (float*)alloc((size_t)N * 4);
    int*   part      = (int*)alloc((size_t)1024 * 4);
    int*   row_start = (int*)alloc((size_t)(N + 1) * 4);
    int*   cursor    = (int*)alloc((size_t)N * 4);
    int*   csr       = (int*)alloc((size_t)E * 4);
    float* csr_w     = (float*)alloc((size_t)E * 4);
    u16*   xh        = (u16*)alloc((size_t)N * 256 * 2);
    u16*   bt1 = (u16*)alloc((size_t)512 * 256 * 2);
    u16*   bt2 = (u16*)alloc((size_t)512 * 512 * 2);
    u16*   bt3 = (u16*)alloc((size_t)64 * 512 * 2);
    u16*   slabA = (u16*)alloc((size_t)Mpad * 512 * 2);
    u16*   slabH = (u16*)alloc((size_t)Mpad * 512 * 2);
    (void)ws_size;

    u16* a1h = slabA;
    u16* a2h = slabA;
    u16* h1h = slabH;
    u16* h2h = slabH;

    const int total8 = N * 32;
    const int nbXs = (total8 + 255) / 256;
    const int nbZero = (N + 255) / 256;
    prep_kernel<<<nbXs + 208 + nbZero, 256, 0, stream>>>(
        x, xh, total8, W1, W2, Wl, bt1, bt2, bt3, deg, cursor, N, nbXs);
    count_deg_kernel<<<(E + 255) / 256, 256, 0, stream>>>(dst, deg, E);
    scan1_kernel<<<nb, 1024, 0, stream>>>(deg, part, N);
    scan3_kernel<<<nb, 1024, 0, stream>>>(deg, part, dinv, row_start, N);
    bucket_kernel<<<(E + 255) / 256, 256, 0, stream>>>(src, dst, row_start, cursor, csr, csr_w, dinv, E);

    // layer 1
    agg_x_kernel<<<2048, 256, 0, stream>>>(xh, a1h, csr, csr_w, row_start, dinv, N);
    gemm256_kernel<true, 2><<<dim3(2, Mpad / 128), 512, 0, stream>>>(
        a1h, bt1, b1, nullptr, h1h, N, 256, 512);

    // layer 2
    agg_h_kernel<<<2048, 256, 0, stream>>>(h1h, a2h, csr, csr_w, row_start, dinv, N);
    gemm256_kernel<true, 2><<<dim3(2, Mpad / 128), 512, 0, stream>>>(
        a2h, bt2, b2, nullptr, h2h, N, 512, 512);

    // output projection
    gemm64_kernel<false><<<dim3(1, Mpad / 128), 256, 0, stream>>>(
        h2h, bt3, bl, out, N, 512, 64);
}

// Round 11
// 405.664 us; speedup vs baseline: 1.0348x; 1.0348x over previous
//
#include <hip/hip_runtime.h>
#include <cstdint>
#include <cstddef>

typedef unsigned short u16;
typedef __attribute__((ext_vector_type(8))) _Float16 f16x8;
typedef __attribute__((ext_vector_type(4))) float f32x4;
typedef __attribute__((ext_vector_type(2))) unsigned u32x2;
typedef __attribute__((ext_vector_type(4))) unsigned u32x4;

// ---------------- fp16 helpers ---------------------------------------------
__device__ __forceinline__ u16 f2h(float f) {
    union { _Float16 h; u16 u; } v; v.h = (_Float16)f;
    return v.u;
}
__device__ __forceinline__ float h2f(u16 b) {
    union { u16 u; _Float16 h; } v; v.u = b;
    return (float)v.h;
}
__device__ __forceinline__ float h2f_lo(unsigned w) { return h2f((u16)(w & 0xFFFFu)); }
__device__ __forceinline__ float h2f_hi(unsigned w) { return h2f((u16)(w >> 16)); }

__device__ __forceinline__ void gload16(const u16* g, u16* l) {
    __builtin_amdgcn_global_load_lds(
        (const __attribute__((address_space(1))) void*)g,
        (__attribute__((address_space(3))) void*)l, 16, 0, 0);
}

// ---------------- prep: zero deg/cursor || x->fp16 || weight transpose -----
__global__ void prep_kernel(const float* __restrict__ x, u16* __restrict__ xh, int total8,
                            const float* __restrict__ W1, const float* __restrict__ W2,
                            const float* __restrict__ Wl, u16* __restrict__ bt1,
                            u16* __restrict__ bt2, u16* __restrict__ bt3,
                            int* __restrict__ deg, int* __restrict__ cursor, int n, int nbXs) {
    const int b = blockIdx.x;
    if (b < nbXs) {
        const int idx = b * 256 + threadIdx.x;
        if (idx >= total8) return;
        const float4 v0 = *(const float4*)(x + (size_t)idx * 8);
        const float4 v1 = *(const float4*)(x + (size_t)idx * 8 + 4);
        alignas(16) u16 h8[8];
        h8[0] = f2h(v0.x); h8[1] = f2h(v0.y); h8[2] = f2h(v0.z); h8[3] = f2h(v0.w);
        h8[4] = f2h(v1.x); h8[5] = f2h(v1.y); h8[6] = f2h(v1.z); h8[7] = f2h(v1.w);
        *(uint4*)(xh + (size_t)idx * 8) = *(const uint4*)h8;
    } else if (b < nbXs + 208) {
        int idx = (b - nbXs) * 256 + threadIdx.x;
        const float* W;
        u16* bt;
        int K, N;
        if (idx < 16384) {
            W = W1; bt = bt1; K = 256; N = 512;
        } else if (idx < 16384 + 32768) {
            idx -= 16384;
            W = W2; bt = bt2; K = 512; N = 512;
        } else if (idx < 16384 + 32768 + 4096) {
            idx -= 16384 + 32768;
            W = Wl; bt = bt3; K = 512; N = 64;
        } else {
            return;
        }
        const int k8 = K >> 3;
        const int nn = idx / k8;
        const int k0 = (idx - nn * k8) * 8;
        alignas(16) u16 h8[8];
#pragma unroll
        for (int j = 0; j < 8; j++) h8[j] = f2h(W[(size_t)(k0 + j) * N + nn]);
        *(uint4*)(bt + (size_t)nn * K + k0) = *(const uint4*)h8;
    } else {
        const int idx = (b - nbXs - 208) * 256 + threadIdx.x;
        if (idx < n) {
            deg[idx] = 0;
            cursor[idx] = 0;
        }
    }
}

// ---------------- graph setup ----------------------------------------------
__global__ void count_deg_kernel(const int* __restrict__ dst, int* __restrict__ deg, int e) {
    int i = blockIdx.x * blockDim.x + threadIdx.x;
    if (i < e) atomicAdd(&deg[dst[i]], 1);
}

__global__ __launch_bounds__(1024)
void scan1_kernel(const int* __restrict__ deg, int* __restrict__ part, int n) {
    __shared__ int sm[1024];
    const int t = threadIdx.x;
    const int i = blockIdx.x * 1024 + t;
    sm[t] = (i < n) ? deg[i] : 0;
    __syncthreads();
    for (int off = 512; off > 0; off >>= 1) {
        if (t < off) sm[t] += sm[t + off];
        __syncthreads();
    }
    if (t == 0) part[blockIdx.x] = sm[0];
}

// scan3 with inlined cross-block prefix (each thread sums part[0..b-1]).
__global__ __launch_bounds__(1024)
void scan3_kernel(const int* __restrict__ deg, const int* __restrict__ part,
                  float* __restrict__ dinv, int* __restrict__ row_start, int n) {
    __shared__ int sm[1024];
    const int t = threadIdx.x;
    const int b = blockIdx.x;
    const int i = b * 1024 + t;
    int base = 0;
    for (int j = 0; j < b; j++) base += part[j];  // <=48 L1-cached loads
    int v = 0;
    if (i < n) v = deg[i];
    sm[t] = v;
    __syncthreads();
    for (int off = 1; off < 1024; off <<= 1) {
        int tv = (t >= off) ? sm[t - off] : 0;
        __syncthreads();
        sm[t] += tv;
        __syncthreads();
    }
    if (i < n) {
        row_start[i] = base + sm[t] - v;
        dinv[i] = rsqrtf(1.0f + (float)v);  // +1 self-loop
    }
    if (i == n - 1) row_start[n] = base + sm[t];
}

__global__ void bucket_kernel(const int* __restrict__ src, const int* __restrict__ dst,
                              const int* __restrict__ row_start, int* __restrict__ cursor,
                              int* __restrict__ csr, float* __restrict__ csr_w,
                              const float* __restrict__ dinv, int e) {
    int i = blockIdx.x * blockDim.x + threadIdx.x;
    if (i < e) {
        int d = dst[i];
        int s = src[i];
        int pos = atomicAdd(&cursor[d], 1);
        int at = row_start[d] + pos;
        csr[at] = s;
        csr_w[at] = dinv[s] * dinv[d];
    }
}

// ---------------- layer-1 aggregation (x fp16 gather, F=256) ---------------
// one-shot block = 4 nodes (wave per node); scheduler load-balances.
__global__ __launch_bounds__(256)
void agg_x_kernel(const u16* __restrict__ xh, u16* __restrict__ oh,
                  const int* __restrict__ csr, const float* __restrict__ csr_w,
                  const int* __restrict__ rs, const float* __restrict__ dinv, int n) {
    const int node = blockIdx.x * 4 + (threadIdx.x >> 6);
    if (node >= n) return;
    const int lane = threadIdx.x & 63;
    const int c0 = lane * 4;
    const int beg = rs[node], end = rs[node + 1];
    float a0 = 0.f, a1 = 0.f, a2 = 0.f, a3 = 0.f;
    int i = beg;
    for (; i + 8 <= end; i += 8) {
        int s[8];
        float w[8];
        uint2 hv[8];
#pragma unroll
        for (int u = 0; u < 8; u++) {
            s[u] = __builtin_nontemporal_load(csr + i + u);
            w[u] = __builtin_nontemporal_load(csr_w + i + u);
        }
#pragma unroll
        for (int u = 0; u < 8; u++) hv[u] = *(const uint2*)(xh + (size_t)s[u] * 256 + c0);
#pragma unroll
        for (int u = 0; u < 8; u++) {
            a0 = fmaf(h2f_lo(hv[u].x), w[u], a0);
            a1 = fmaf(h2f_hi(hv[u].x), w[u], a1);
            a2 = fmaf(h2f_lo(hv[u].y), w[u], a2);
            a3 = fmaf(h2f_hi(hv[u].y), w[u], a3);
        }
    }
    for (; i < end; i++) {
        const int sv = csr[i];
        const float w = csr_w[i];
        uint2 hv = *(const uint2*)(xh + (size_t)sv * 256 + c0);
        a0 = fmaf(h2f_lo(hv.x), w, a0);
        a1 = fmaf(h2f_hi(hv.x), w, a1);
        a2 = fmaf(h2f_lo(hv.y), w, a2);
        a3 = fmaf(h2f_hi(hv.y), w, a3);
    }
    {
        const float dn = dinv[node];
        const float ws = dn * dn;
        uint2 hv = *(const uint2*)(xh + (size_t)node * 256 + c0);
        a0 = fmaf(h2f_lo(hv.x), ws, a0);
        a1 = fmaf(h2f_hi(hv.x), ws, a1);
        a2 = fmaf(h2f_lo(hv.y), ws, a2);
        a3 = fmaf(h2f_hi(hv.y), ws, a3);
    }
    u32x2 ho;
    ho.x = (unsigned)f2h(a0) | ((unsigned)f2h(a1) << 16);
    ho.y = (unsigned)f2h(a2) | ((unsigned)f2h(a3) << 16);
    __builtin_nontemporal_store(ho, (u32x2*)(oh + (size_t)node * 256 + c0));
}

// ---------------- layer-2 aggregation (h1 fp16 gather, F=512) --------------
__global__ __launch_bounds__(256)
void agg_h_kernel(const u16* __restrict__ hin, u16* __restrict__ oh,
                  const int* __restrict__ csr, const float* __restrict__ csr_w,
                  const int* __restrict__ rs, const float* __restrict__ dinv, int n) {
    const int node = blockIdx.x * 4 + (threadIdx.x >> 6);
    if (node >= n) return;
    const int lane = threadIdx.x & 63;
    const int c0 = lane * 8;
    const int beg = rs[node], end = rs[node + 1];
    float a[8];
#pragma unroll
    for (int j = 0; j < 8; j++) a[j] = 0.f;
    int i = beg;
    for (; i + 8 <= end; i += 8) {
        int s[8];
        float w[8];
        uint4 hv[8];
#pragma unroll
        for (int u = 0; u < 8; u++) {
            s[u] = __builtin_nontemporal_load(csr + i + u);
            w[u] = __builtin_nontemporal_load(csr_w + i + u);
        }
#pragma unroll
        for (int u = 0; u < 8; u++) hv[u] = *(const uint4*)(hin + (size_t)s[u] * 512 + c0);
#pragma unroll
        for (int u = 0; u < 8; u++) {
            a[0] = fmaf(h2f_lo(hv[u].x), w[u], a[0]);
            a[1] = fmaf(h2f_hi(hv[u].x), w[u], a[1]);
            a[2] = fmaf(h2f_lo(hv[u].y), w[u], a[2]);
            a[3] = fmaf(h2f_hi(hv[u].y), w[u], a[3]);
            a[4] = fmaf(h2f_lo(hv[u].z), w[u], a[4]);
            a[5] = fmaf(h2f_hi(hv[u].z), w[u], a[5]);
            a[6] = fmaf(h2f_lo(hv[u].w), w[u], a[6]);
            a[7] = fmaf(h2f_hi(hv[u].w), w[u], a[7]);
        }
    }
    for (; i < end; i++) {
        const int sv = csr[i];
        const float w = csr_w[i];
        uint4 hv = *(const uint4*)(hin + (size_t)sv * 512 + c0);
        a[0] = fmaf(h2f_lo(hv.x), w, a[0]);
        a[1] = fmaf(h2f_hi(hv.x), w, a[1]);
        a[2] = fmaf(h2f_lo(hv.y), w, a[2]);
        a[3] = fmaf(h2f_hi(hv.y), w, a[3]);
        a[4] = fmaf(h2f_lo(hv.z), w, a[4]);
        a[5] = fmaf(h2f_hi(hv.z), w, a[5]);
        a[6] = fmaf(h2f_lo(hv.w), w, a[6]);
        a[7] = fmaf(h2f_hi(hv.w), w, a[7]);
    }
    {
        const float dn = dinv[node];
        const float ws = dn * dn;
        uint4 hv = *(const uint4*)(hin + (size_t)node * 512 + c0);
        a[0] = fmaf(h2f_lo(hv.x), ws, a[0]);
        a[1] = fmaf(h2f_hi(hv.x), ws, a[1]);
        a[2] = fmaf(h2f_lo(hv.y), ws, a[2]);
        a[3] = fmaf(h2f_hi(hv.y), ws, a[3]);
        a[4] = fmaf(h2f_lo(hv.z), ws, a[4]);
        a[5] = fmaf(h2f_hi(hv.z), ws, a[5]);
        a[6] = fmaf(h2f_lo(hv.w), ws, a[6]);
        a[7] = fmaf(h2f_hi(hv.w), ws, a[7]);
    }
    u32x4 ho;
#pragma unroll
    for (int j = 0; j < 4; j++)
        ho[j] = (unsigned)f2h(a[2 * j]) | ((unsigned)f2h(a[2 * j + 1]) << 16);
    __builtin_nontemporal_store(ho, (u32x4*)(oh + (size_t)node * 512 + c0));
}

// ---------------- fp16 MFMA GEMM, BM=128 BN=256, 8 waves, LDS dbuf ---------
template <bool RELU, int OUTMODE>
__global__ __launch_bounds__(512)
void gemm256_kernel(const u16* __restrict__ A, const u16* __restrict__ Bt,
                    const float* __restrict__ bias,
                    float* __restrict__ Cf, u16* __restrict__ Ch,
                    int M, int K, int Nn) {
    __shared__ u16 sA[2][128 * 32], sB[2][256 * 32];

    const int gx = gridDim.x;
    const int nwg = gx * gridDim.y;
    const int orig = blockIdx.y * gx + blockIdx.x;
    const int q8 = nwg >> 3, r8 = nwg & 7;
    const int xcd = orig & 7, lin = orig >> 3;
    const int wg = (xcd < r8 ? xcd * (q8 + 1) : r8 * (q8 + 1) + (xcd - r8) * q8) + lin;
    const int mt = wg / gx;
    const int nt_ = wg - mt * gx;
    const int m0 = mt * 128, n0 = nt_ * 256;

    const int tid = threadIdx.x;
    const int lane = tid & 63;
    const int wid = tid >> 6;
    const int wm = (wid >> 2) * 64;
    const int wn = (wid & 3) * 64;

    const int srow = tid >> 2;
    const int gslot = (tid & 3) ^ ((tid >> 3) & 3);
    const int lbase = wid * 16 * 32;  // u16 units

    const u16* gA  = A  + (size_t)(m0 + srow) * K + gslot * 8;
    const u16* gB0 = Bt + (size_t)(n0 + srow) * K + gslot * 8;
    const u16* gB1 = Bt + (size_t)(n0 + 128 + srow) * K + gslot * 8;

    int offA[4], offB[4];
    const int q = lane >> 4;
#pragma unroll
    for (int i = 0; i < 4; i++) {
        int r = wm + i * 16 + (lane & 15);
        offA[i] = r * 32 + ((q ^ ((r >> 1) & 3)) * 8);
    }
#pragma unroll
    for (int j = 0; j < 4; j++) {
        int r = wn + j * 16 + (lane & 15);
        offB[j] = r * 32 + ((q ^ ((r >> 1) & 3)) * 8);
    }

    f32x4 acc[4][4];
#pragma unroll
    for (int i = 0; i < 4; i++)
#pragma unroll
        for (int j = 0; j < 4; j++) acc[i][j] = (f32x4){0.f, 0.f, 0.f, 0.f};

    auto stage = [&](int k0, int b) {
        gload16(gA + k0, sA[b] + lbase);
        gload16(gB0 + k0, sB[b] + lbase);
        gload16(gB1 + k0, sB[b] + 128 * 32 + lbase);
    };

    const int ntiles = K >> 5;
    stage(0, 0);
    for (int t = 0; t < ntiles; ++t) {
        const int cur = t & 1;
        __builtin_amdgcn_s_barrier();
        if (t + 1 < ntiles) {
            stage((t + 1) << 5, cur ^ 1);
            asm volatile("s_waitcnt vmcnt(3)" ::: "memory");
        } else {
            asm volatile("s_waitcnt vmcnt(0)" ::: "memory");
        }
        __builtin_amdgcn_s_barrier();
        __builtin_amdgcn_sched_barrier(0);

        f16x8 af[4], bf4[4];
#pragma unroll
        for (int i = 0; i < 4; i++) af[i] = *(const f16x8*)(sA[cur] + offA[i]);
#pragma unroll
        for (int j = 0; j < 4; j++) bf4[j] = *(const f16x8*)(sB[cur] + offB[j]);
#pragma unroll
        for (int i = 0; i < 4; i++)
#pragma unroll
            for (int j = 0; j < 4; j++)
                acc[i][j] = __builtin_amdgcn_mfma_f32_16x16x32_f16(af[i], bf4[j], acc[i][j], 0, 0, 0);
    }

    const int cn = lane & 15;
    const int cm = (lane >> 4) * 4;
#pragma unroll
    for (int i = 0; i < 4; i++) {
#pragma unroll
        for (int j = 0; j < 4; j++) {
            const int col = n0 + wn + j * 16 + cn;
            const float bv = bias[col];
#pragma unroll
            for (int r = 0; r < 4; r++) {
                const int row = m0 + wm + i * 16 + cm + r;
                if (row < M) {
                    float v = acc[i][j][r] + bv;
                    if (RELU) v = fmaxf(v, 0.f);
                    if constexpr (OUTMODE == 2) {
                        Ch[(size_t)row * Nn + col] = f2h(v);
                    } else {
                        Cf[(size_t)row * Nn + col] = v;
                    }
                }
            }
        }
    }
}

// ---------------- fp16 MFMA GEMM, BM=128 BN=64, 4 waves (2x2) --------------
template <bool RELU>
__global__ __launch_bounds__(256)
void gemm64_kernel(const u16* __restrict__ A, const u16* __restrict__ Bt,
                   const float* __restrict__ bias, float* __restrict__ Cf,
                   int M, int K, int Nn) {
    __shared__ u16 sA[128 * 32], sB[64 * 32];

    const int nwg = gridDim.y;
    const int orig = blockIdx.y;
    const int q8 = nwg >> 3, r8 = nwg & 7;
    const int xcd = orig & 7, lin = orig >> 3;
    const int wg = (xcd < r8 ? xcd * (q8 + 1) : r8 * (q8 + 1) + (xcd - r8) * q8) + lin;
    const int m0 = wg * 128, n0 = 0;

    const int tid = threadIdx.x;
    const int lane = tid & 63;
    const int wid = tid >> 6;
    const int wm = (wid >> 1) * 64;
    const int wn = (wid & 1) * 32;

    const int srow = tid >> 2;
    const int gslot = (tid & 3) ^ ((tid >> 3) & 3);
    const int lbase = wid * 16 * 32;

    const u16* gA0 = A + (size_t)(m0 + srow) * K + gslot * 8;
    const u16* gA1 = A + (size_t)(m0 + 64 + srow) * K + gslot * 8;
    const u16* gB0 = Bt + (size_t)(n0 + srow) * K + gslot * 8;

    int offA[4], offB[2];
    const int q = lane >> 4;
#pragma unroll
    for (int i = 0; i < 4; i++) {
        int r = wm + i * 16 + (lane & 15);
        offA[i] = r * 32 + ((q ^ ((r >> 1) & 3)) * 8);
    }
#pragma unroll
    for (int j = 0; j < 2; j++) {
        int r = wn + j * 16 + (lane & 15);
        offB[j] = r * 32 + ((q ^ ((r >> 1) & 3)) * 8);
    }

    f32x4 acc[4][2];
#pragma unroll
    for (int i = 0; i < 4; i++)
#pragma unroll
        for (int j = 0; j < 2; j++) acc[i][j] = (f32x4){0.f, 0.f, 0.f, 0.f};

    auto stage = [&](int k0) {
        gload16(gA0 + k0, sA + lbase);
        gload16(gA1 + k0, sA + 64 * 32 + lbase);
        gload16(gB0 + k0, sB + lbase);
    };

    stage(0);
    for (int k0 = 0; k0 < K; k0 += 32) {
        __syncthreads();
        f16x8 af[4], bf4[2];
#pragma unroll
        for (int i = 0; i < 4; i++) af[i] = *(const f16x8*)(sA + offA[i]);
#pragma unroll
        for (int j = 0; j < 2; j++) bf4[j] = *(const f16x8*)(sB + offB[j]);
#pragma unroll
        for (int i = 0; i < 4; i++)
#pragma unroll
            for (int j = 0; j < 2; j++)
                acc[i][j] = __builtin_amdgcn_mfma_f32_16x16x32_f16(af[i], bf4[j], acc[i][j], 0, 0, 0);
        __syncthreads();
        if (k0 + 32 < K) stage(k0 + 32);
    }

    const int cn = lane & 15;
    const int cm = (lane >> 4) * 4;
#pragma unroll
    for (int i = 0; i < 4; i++) {
#pragma unroll
        for (int j = 0; j < 2; j++) {
            const int col = wn + j * 16 + cn;
            const float bv = bias[col];
#pragma unroll
            for (int r = 0; r < 4; r++) {
                const int row = m0 + wm + i * 16 + cm + r;
                if (row < M) {
                    float v = acc[i][j][r] + bv;
                    if (RELU) v = fmaxf(v, 0.f);
                    Cf[(size_t)row * Nn + col] = v;
                }
            }
        }
    }
}

// ---------------------------------------------------------------------------
extern "C" void kernel_launch(void* const* d_in, const int* in_sizes, int n_in,
                              void* d_out, int out_size, void* d_ws, size_t ws_size,
                              hipStream_t stream) {
    const float* x  = (const float*)d_in[0];
    const int*   ei = (const int*)d_in[1];
    const float* W1 = (const float*)d_in[2];
    const float* b1 = (const float*)d_in[3];
    const float* W2 = (const float*)d_in[4];
    const float* b2 = (const float*)d_in[5];
    const float* Wl = (const float*)d_in[6];
    const float* bl = (const float*)d_in[7];
    float* out = (float*)d_out;

    const int N = in_sizes[0] / 256;  // 50000
    const int E = in_sizes[1] / 2;    // 800000
    const int Mpad = ((N + 127) / 128) * 128;  // 50048
    const int nb = (N + 1023) / 1024;
    const int* src = ei;
    const int* dst = ei + E;

    size_t off = 0;
    auto alloc = [&](size_t bytes) -> void* {
        void* p = (char*)d_ws + off;
        off += (bytes + 255) & ~(size_t)255;
        return p;
    };
    int*   deg       = (int*)alloc((size_t)N * 4);
    float* dinv      = (float*)alloc((size_t)N * 4);
    int*   part      = (int*)alloc((size_t)1024 * 4);
    int*   row_start = (int*)alloc((size_t)(N + 1) * 4);
    int*   cursor    = (int*)alloc((size_t)N * 4);
    int*   csr       = (int*)alloc((size_t)E * 4);
    float* csr_w     = (float*)alloc((size_t)E * 4);
    u16*   xh        = (u16*)alloc((size_t)N * 256 * 2);
    u16*   bt1 = (u16*)alloc((size_t)512 * 256 * 2);
    u16*   bt2 = (u16*)alloc((size_t)512 * 512 * 2);
    u16*   bt3 = (u16*)alloc((size_t)64 * 512 * 2);
    u16*   slabA = (u16*)alloc((size_t)Mpad * 512 * 2);
    u16*   slabH = (u16*)alloc((size_t)Mpad * 512 * 2);
    (void)ws_size;

    u16* a1h = slabA;
    u16* a2h = slabA;
    u16* h1h = slabH;
    u16* h2h = slabH;

    const int total8 = N * 32;
    const int nbXs = (total8 + 255) / 256;
    const int nbZero = (N + 255) / 256;
    prep_kernel<<<nbXs + 208 + nbZero, 256, 0, stream>>>(
        x, xh, total8, W1, W2, Wl, bt1, bt2, bt3, deg, cursor, N, nbXs);
    count_deg_kernel<<<(E + 255) / 256, 256, 0, stream>>>(dst, deg, E);
    scan1_kernel<<<nb, 1024, 0, stream>>>(deg, part, N);
    scan3_kernel<<<nb, 1024, 0, stream>>>(deg, part, dinv, row_start, N);
    bucket_kernel<<<(E + 255) / 256, 256, 0, stream>>>(src, dst, row_start, cursor, csr, csr_w, dinv, E);

    // layer 1
    agg_x_kernel<<<(N + 3) / 4, 256, 0, stream>>>(xh, a1h, csr, csr_w, row_start, dinv, N);
    gemm256_kernel<true, 2><<<dim3(2, Mpad / 128), 512, 0, stream>>>(
        a1h, bt1, b1, nullptr, h1h, N, 256, 512);

    // layer 2
    agg_h_kernel<<<(N + 3) / 4, 256, 0, stream>>>(h1h, a2h, csr, csr_w, row_start, dinv, N);
    gemm256_kernel<true, 2><<<dim3(2, Mpad / 128), 512, 0, stream>>>(
        a2h, bt2, b2, nullptr, h2h, N, 512, 512);

    // output projection
    gemm64_kernel<false><<<dim3(1, Mpad / 128), 256, 0, stream>>>(
        h2h, bt3, bl, out, N, 512, 64);
}